// Round 1
// baseline (1425.070 us; speedup 1.0000x reference)
//
#include <hip/hip_runtime.h>

#define DI __device__ __forceinline__

#define B_ 8
#define N_ 4096
#define S_ 1024
#define K_ 32
#define M_TOT (B_ * S_ * K_)   // 262144 rows
#define NBLK 2048              // M_TOT / 128

// Exact-IEEE squared distance, matching numpy f32 eval order ((dx*dx+dy*dy)+dz*dz),
// _rn intrinsics block FMA contraction so indices match the reference bit-exactly.
DI float sqdist_rn(float ax, float ay, float az, float bx, float by, float bz) {
    float dx = __fsub_rn(ax, bx);
    float dy = __fsub_rn(ay, by);
    float dz = __fsub_rn(az, bz);
    return __fadd_rn(__fadd_rn(__fmul_rn(dx, dx), __fmul_rn(dy, dy)), __fmul_rn(dz, dz));
}

DI unsigned short f2b(float f) {  // f32 -> bf16 RNE
    unsigned u = __float_as_uint(f);
    return (unsigned short)((u + 0x7FFFu + ((u >> 16) & 1u)) >> 16);
}
DI float b2f(unsigned short h) { return __uint_as_float(((unsigned)h) << 16); }

// ---------------- FPS: one block per batch, sequential 1024-step scan ----------------
__global__ __launch_bounds__(512) void fps_kernel(const float* __restrict__ xyz,
                                                  float* __restrict__ new_xyz) {
    const int b = blockIdx.x;
    const int t = threadIdx.x;
    const float* X = xyz + (size_t)b * (N_ * 3);
    float px[8], py[8], pz[8], dd[8];
#pragma unroll
    for (int j = 0; j < 8; ++j) {
        int p = t + 512 * j;
        px[j] = X[p * 3 + 0];
        py[j] = X[p * 3 + 1];
        pz[j] = X[p * 3 + 2];
        dd[j] = 1e10f;
    }
    __shared__ float cent[3];
    __shared__ unsigned long long part[8];
    if (t == 0) {
        cent[0] = px[0]; cent[1] = py[0]; cent[2] = pz[0];
        new_xyz[(size_t)b * (S_ * 3) + 0] = px[0];
        new_xyz[(size_t)b * (S_ * 3) + 1] = py[0];
        new_xyz[(size_t)b * (S_ * 3) + 2] = pz[0];
    }
    __syncthreads();
    for (int i = 1; i < S_; ++i) {
        float cx = cent[0], cy = cent[1], cz = cent[2];
        float bd = -1.0f;
        int bp = 0;
#pragma unroll
        for (int j = 0; j < 8; ++j) {
            float d = sqdist_rn(px[j], py[j], pz[j], cx, cy, cz);
            dd[j] = fminf(dd[j], d);
            if (dd[j] > bd) { bd = dd[j]; bp = t + 512 * j; }  // ascending p -> first-max
        }
        // key: max dist wins; tie -> lower point index wins (matches np.argmax)
        unsigned long long key =
            ((unsigned long long)__float_as_uint(bd) << 32) |
            (unsigned long long)(0xFFFFFFFFu - (unsigned)bp);
#pragma unroll
        for (int m = 32; m >= 1; m >>= 1) {
            unsigned long long o = __shfl_xor(key, m);
            if (o > key) key = o;
        }
        if ((t & 63) == 0) part[t >> 6] = key;
        __syncthreads();
        unsigned long long k = part[0];
#pragma unroll
        for (int w = 1; w < 8; ++w) { unsigned long long pw = part[w]; if (pw > k) k = pw; }
        unsigned gidx = 0xFFFFFFFFu - (unsigned)(k & 0xFFFFFFFFull);
        if (t == (int)(gidx & 511u)) {
            int j = (int)(gidx >> 9);
            cent[0] = px[j]; cent[1] = py[j]; cent[2] = pz[j];
            size_t o3 = ((size_t)b * S_ + i) * 3;
            new_xyz[o3 + 0] = px[j];
            new_xyz[o3 + 1] = py[j];
            new_xyz[o3 + 2] = pz[j];
        }
        __syncthreads();
    }
}

// ---------------- Ball query: one wave per center, ordered compaction ----------------
__global__ __launch_bounds__(256) void qb_kernel(const float* __restrict__ xyz,
                                                 const float* __restrict__ new_xyz,
                                                 int* __restrict__ idxbuf) {
    const int c = blockIdx.x * 4 + (threadIdx.x >> 6);
    const int lane = threadIdx.x & 63;
    const int b = c >> 10;
    const float* X = xyz + (size_t)b * (N_ * 3);
    const float cx = new_xyz[c * 3 + 0];
    const float cy = new_xyz[c * 3 + 1];
    const float cz = new_xyz[c * 3 + 2];
    int* out = idxbuf + (size_t)c * K_;
    int taken = 0, first = -1;
    for (int ch = 0; ch < 64; ++ch) {
        int p = ch * 64 + lane;
        float d = sqdist_rn(X[p * 3 + 0], X[p * 3 + 1], X[p * 3 + 2], cx, cy, cz);
        bool ok = (d <= 0.25f);  // sqr > r^2 excluded => include <=
        unsigned long long m = __ballot(ok);
        if (first < 0 && m) first = ch * 64 + (__ffsll((unsigned long long)m) - 1);
        int pos = taken + (int)__popcll(m & ((1ull << lane) - 1ull));
        if (ok && pos < K_) out[pos] = p;
        taken += (int)__popcll(m);
        if (taken >= K_) break;
    }
    int filled = taken < K_ ? taken : K_;
    if (lane >= filled && lane < K_) out[lane] = first;
}

// ---------------- shared GEMM tile: 128 rows x (16*CC) outs, f32 register tile ----------------
template <int FS, int SLOTS, int CC>
DI void gemm_tile(const float* __restrict__ feat, const float* __restrict__ wl,
                  const float* __restrict__ bias, unsigned short* __restrict__ yout,
                  float* __restrict__ ps, float* __restrict__ pq,
                  int r0, int tid, int blk) {
    const int tr = tid & 15;
    const int tc = tid >> 4;
    float acc[8][CC];
#pragma unroll
    for (int rr = 0; rr < 8; ++rr)
#pragma unroll
        for (int cc = 0; cc < CC; ++cc) acc[rr][cc] = 0.0f;

#pragma unroll 2
    for (int sl = 0; sl < SLOTS; ++sl) {
        float4 xv[8], wv[CC];
#pragma unroll
        for (int rr = 0; rr < 8; ++rr)
            xv[rr] = *(const float4*)&feat[(tr + 16 * rr) * FS + 4 * sl];
#pragma unroll
        for (int cc = 0; cc < CC; ++cc)
            wv[cc] = *(const float4*)&wl[(tc + 16 * cc) * FS + 4 * sl];
#pragma unroll
        for (int rr = 0; rr < 8; ++rr)
#pragma unroll
            for (int cc = 0; cc < CC; ++cc)
                acc[rr][cc] = fmaf(xv[rr].x, wv[cc].x,
                               fmaf(xv[rr].y, wv[cc].y,
                                fmaf(xv[rr].z, wv[cc].z,
                                 fmaf(xv[rr].w, wv[cc].w, acc[rr][cc]))));
    }
    float s1[CC], s2[CC];
#pragma unroll
    for (int cc = 0; cc < CC; ++cc) {
        const int och = tc + 16 * cc;
        const float bv = bias[och];
        s1[cc] = 0.0f; s2[cc] = 0.0f;
#pragma unroll
        for (int rr = 0; rr < 8; ++rr) {
            float y = acc[rr][cc] + bv;
            const int gr = r0 + tr + 16 * rr;
            yout[(size_t)gr * (16 * CC) + och] = f2b(y);
            s1[cc] += y;
            s2[cc] = fmaf(y, y, s2[cc]);
        }
    }
    // lanes 0..15 within each 16-lane group share tc -> butterfly over tr gives
    // complete per-channel totals for this block; no atomics needed.
#pragma unroll
    for (int m = 1; m < 16; m <<= 1) {
#pragma unroll
        for (int cc = 0; cc < CC; ++cc) {
            s1[cc] += __shfl_xor(s1[cc], m);
            s2[cc] += __shfl_xor(s2[cc], m);
        }
    }
    if ((tid & 15) == 0) {
#pragma unroll
        for (int cc = 0; cc < CC; ++cc) {
            const int och = tc + 16 * cc;
            ps[och * NBLK + blk] = s1[cc];
            pq[och * NBLK + blk] = s2[cc];
        }
    }
}

// ---------------- Layer 1: gather(xyz, xyz-center, points) + GEMM 70->64 ----------------
__global__ __launch_bounds__(256) void layer1_kernel(
    const float* __restrict__ xyz, const float* __restrict__ points,
    const float* __restrict__ new_xyz, const int* __restrict__ idxbuf,
    const float* __restrict__ W, const float* __restrict__ bias,
    unsigned short* __restrict__ yout, float* __restrict__ ps, float* __restrict__ pq) {
    const int tid = threadIdx.x;
    const int blk = blockIdx.x;
    const int r0 = blk * 128;
    __shared__ float feat[128 * 76];   // channels: 0..5 xyz/norm, 6..7 zero pad, 8..71 points
    __shared__ float wl[64 * 76];
    for (int jj = tid; jj < 64 * 70; jj += 256) {
        int o = jj / 70;
        int i = jj - o * 70;
        int mch = (i < 6) ? i : (i + 2);
        wl[o * 76 + mch] = W[jj];
    }
    if (tid < 128) wl[(tid >> 1) * 76 + 6 + (tid & 1)] = 0.0f;
    {
        const int row = tid >> 1, h = tid & 1;
        const int gr = r0 + row;
        const int b = gr >> 15;
        const int s = (gr >> 5) & 1023;
        const int pi = idxbuf[gr];
        const float* P = points + ((size_t)b * N_ + pi) * 64 + h * 32;
        float* fr = &feat[row * 76];
#pragma unroll
        for (int q = 0; q < 8; ++q) {
            float4 v = *(const float4*)(P + 4 * q);
            *(float4*)(fr + 8 + h * 32 + 4 * q) = v;
        }
        if (h == 0) {
            size_t pb = ((size_t)b * N_ + pi) * 3;
            float x = xyz[pb + 0], y = xyz[pb + 1], z = xyz[pb + 2];
            const float* C = new_xyz + ((size_t)b * S_ + s) * 3;
            fr[0] = x; fr[1] = y; fr[2] = z;
            fr[3] = x - C[0]; fr[4] = y - C[1]; fr[5] = z - C[2];
            fr[6] = 0.0f; fr[7] = 0.0f;
        }
    }
    __syncthreads();
    gemm_tile<76, 18, 4>(feat, wl, bias, yout, ps, pq, r0, tid, blk);
}

// ---------------- Layers 2/3: BN(prev)+ReLU on load, GEMM 64->OC ----------------
template <int OC>
__global__ __launch_bounds__(256) void layer23_kernel(
    const unsigned short* __restrict__ yin,
    const float* __restrict__ scale, const float* __restrict__ shift,
    const float* __restrict__ W, const float* __restrict__ bias,
    unsigned short* __restrict__ yout, float* __restrict__ ps, float* __restrict__ pq) {
    const int tid = threadIdx.x;
    const int blk = blockIdx.x;
    const int r0 = blk * 128;
    __shared__ float feat[128 * 68];
    __shared__ float wl[OC * 68];
    __shared__ float ssc[64], ssh[64];
    if (tid < 64) { ssc[tid] = scale[tid]; ssh[tid] = shift[tid]; }
    for (int jj = tid; jj < OC * 64; jj += 256) {
        int o = jj >> 6, i = jj & 63;
        wl[o * 68 + i] = W[jj];
    }
    __syncthreads();
    {
        const int row = tid >> 1, h = tid & 1;
        const int gr = r0 + row;
        const uint4* src = (const uint4*)(yin + (size_t)gr * 64 + h * 32);
        float* fr = &feat[row * 68 + h * 32];
#pragma unroll
        for (int q = 0; q < 4; ++q) {
            uint4 u = src[q];
            const int cb = h * 32 + q * 8;
            float f0 = fmaxf(fmaf(__uint_as_float(u.x << 16),         ssc[cb + 0], ssh[cb + 0]), 0.f);
            float f1 = fmaxf(fmaf(__uint_as_float(u.x & 0xFFFF0000u), ssc[cb + 1], ssh[cb + 1]), 0.f);
            float f2 = fmaxf(fmaf(__uint_as_float(u.y << 16),         ssc[cb + 2], ssh[cb + 2]), 0.f);
            float f3 = fmaxf(fmaf(__uint_as_float(u.y & 0xFFFF0000u), ssc[cb + 3], ssh[cb + 3]), 0.f);
            float f4 = fmaxf(fmaf(__uint_as_float(u.z << 16),         ssc[cb + 4], ssh[cb + 4]), 0.f);
            float f5 = fmaxf(fmaf(__uint_as_float(u.z & 0xFFFF0000u), ssc[cb + 5], ssh[cb + 5]), 0.f);
            float f6 = fmaxf(fmaf(__uint_as_float(u.w << 16),         ssc[cb + 6], ssh[cb + 6]), 0.f);
            float f7 = fmaxf(fmaf(__uint_as_float(u.w & 0xFFFF0000u), ssc[cb + 7], ssh[cb + 7]), 0.f);
            *(float4*)(fr + 8 * q)     = make_float4(f0, f1, f2, f3);
            *(float4*)(fr + 8 * q + 4) = make_float4(f4, f5, f6, f7);
        }
    }
    __syncthreads();
    gemm_tile<68, 16, OC / 16>(feat, wl, bias, yout, ps, pq, r0, tid, blk);
}

// ---------------- BN stats reduce -> scale/shift ----------------
__global__ __launch_bounds__(256) void bn_reduce_kernel(
    const float* __restrict__ ps, const float* __restrict__ pq,
    const float* __restrict__ gamma, const float* __restrict__ beta,
    float* __restrict__ scale, float* __restrict__ shift) {
    const int o = blockIdx.x, t = threadIdx.x;
    float s1 = 0.f, s2 = 0.f;
    for (int i = t; i < NBLK; i += 256) {
        s1 += ps[o * NBLK + i];
        s2 += pq[o * NBLK + i];
    }
#pragma unroll
    for (int m = 32; m >= 1; m >>= 1) { s1 += __shfl_xor(s1, m); s2 += __shfl_xor(s2, m); }
    __shared__ float a1[4], a2[4];
    if ((t & 63) == 0) { a1[t >> 6] = s1; a2[t >> 6] = s2; }
    __syncthreads();
    if (t == 0) {
        float S1 = a1[0] + a1[1] + a1[2] + a1[3];
        float S2 = a2[0] + a2[1] + a2[2] + a2[3];
        const float inv = 1.0f / (float)M_TOT;
        float mean = S1 * inv;
        float var = S2 * inv - mean * mean;
        if (var < 0.f) var = 0.f;
        float rstd = 1.0f / sqrtf(var + 1e-5f);
        float sc = rstd * gamma[o];
        scale[o] = sc;
        shift[o] = beta[o] - mean * sc;
    }
}

// ---------------- BN3 + ReLU + max over K ----------------
__global__ __launch_bounds__(256) void pool_kernel(
    const unsigned short* __restrict__ y3,
    const float* __restrict__ scale, const float* __restrict__ shift,
    float* __restrict__ outp) {
    const int grp = blockIdx.x * 2 + (threadIdx.x >> 7);
    const int ch = threadIdx.x & 127;
    const unsigned short* Y = y3 + (size_t)grp * (K_ * 128) + ch;
    const float sc = scale[ch], sh = shift[ch];
    float m = -1e30f;
#pragma unroll 8
    for (int k = 0; k < K_; ++k) {
        float v = b2f(Y[k * 128]);
        m = fmaxf(m, fmaf(v, sc, sh));
    }
    outp[(size_t)grp * 128 + ch] = fmaxf(m, 0.0f);  // relu commutes with max
}

extern "C" void kernel_launch(void* const* d_in, const int* in_sizes, int n_in,
                              void* d_out, int out_size, void* d_ws, size_t ws_size,
                              hipStream_t stream) {
    const float* xyz    = (const float*)d_in[0];
    const float* points = (const float*)d_in[1];
    const float* w0  = (const float*)d_in[2];
    const float* b0  = (const float*)d_in[3];
    const float* g0  = (const float*)d_in[4];
    const float* be0 = (const float*)d_in[5];
    const float* w1  = (const float*)d_in[6];
    const float* b1  = (const float*)d_in[7];
    const float* g1  = (const float*)d_in[8];
    const float* be1 = (const float*)d_in[9];
    const float* w2  = (const float*)d_in[10];
    const float* b2  = (const float*)d_in[11];
    const float* g2  = (const float*)d_in[12];
    const float* be2 = (const float*)d_in[13];

    float* out = (float*)d_out;           // [0,24576) new_xyz, [24576,...) new_points
    char* ws = (char*)d_ws;
    int*   idxbuf = (int*)ws;                              // 1 MB
    float* ps  = (float*)(ws + (1 << 20));                 // 1 MB (128ch x 2048 blk)
    float* pq  = (float*)(ws + (2 << 20));                 // 1 MB
    float* st  = (float*)(ws + (3 << 20));                 // scale/shift x3 layers
    float *sc0 = st,        *sh0 = st + 128;
    float *sc1 = st + 256,  *sh1 = st + 384;
    float *sc2 = st + 512,  *sh2 = st + 640;
    unsigned short* y1 = (unsigned short*)(ws + (4 << 20));   // 32 MB (bf16)
    unsigned short* y3 = y1;                                  // 64 MB, reuses y1 (dead)
    unsigned short* y2 = (unsigned short*)(ws + (68 << 20));  // 32 MB
    // total ws footprint: 100 MB

    fps_kernel<<<8, 512, 0, stream>>>(xyz, out);
    qb_kernel<<<2048, 256, 0, stream>>>(xyz, out, idxbuf);
    layer1_kernel<<<NBLK, 256, 0, stream>>>(xyz, points, out, idxbuf, w0, b0, y1, ps, pq);
    bn_reduce_kernel<<<64, 256, 0, stream>>>(ps, pq, g0, be0, sc0, sh0);
    layer23_kernel<64><<<NBLK, 256, 0, stream>>>(y1, sc0, sh0, w1, b1, y2, ps, pq);
    bn_reduce_kernel<<<64, 256, 0, stream>>>(ps, pq, g1, be1, sc1, sh1);
    layer23_kernel<128><<<NBLK, 256, 0, stream>>>(y2, sc1, sh1, w2, b2, y3, ps, pq);
    bn_reduce_kernel<<<128, 256, 0, stream>>>(ps, pq, g2, be2, sc2, sh2);
    pool_kernel<<<4096, 256, 0, stream>>>(y3, sc2, sh2, out + 24576);
}

// Round 2
// 1140.874 us; speedup vs baseline: 1.2491x; 1.2491x over previous
//
#include <hip/hip_runtime.h>

#define DI __device__ __forceinline__

#define B_ 8
#define N_ 4096
#define S_ 1024
#define K_ 32
#define M_TOT (B_ * S_ * K_)   // 262144 rows
#define NBLK 2048              // M_TOT / 128

// Exact-IEEE squared distance, matching numpy f32 eval order ((dx*dx+dy*dy)+dz*dz),
// _rn intrinsics block FMA contraction so indices match the reference bit-exactly.
DI float sqdist_rn(float ax, float ay, float az, float bx, float by, float bz) {
    float dx = __fsub_rn(ax, bx);
    float dy = __fsub_rn(ay, by);
    float dz = __fsub_rn(az, bz);
    return __fadd_rn(__fadd_rn(__fmul_rn(dx, dx), __fmul_rn(dy, dy)), __fmul_rn(dz, dz));
}

DI unsigned short f2b(float f) {  // f32 -> bf16 RNE
    unsigned u = __float_as_uint(f);
    return (unsigned short)((u + 0x7FFFu + ((u >> 16) & 1u)) >> 16);
}
DI float b2f(unsigned short h) { return __uint_as_float(((unsigned)h) << 16); }

// ---------------- FPS: one block per batch, 1 barrier/step, LDS coord table ----------------
// Critical path per step: dist-compute -> 6-stage u64 butterfly -> barrier ->
// redundant 8-partial reduce (all threads) -> broadcast LDS read of winner coords.
// No serialized "publish centroid" section; partials double-buffered (write to
// the same buffer is always two barriers after its readers).
__global__ __launch_bounds__(512) void fps_kernel(const float* __restrict__ xyz,
                                                  float* __restrict__ new_xyz) {
    const int b = blockIdx.x;
    const int t = threadIdx.x;
    const float* X = xyz + (size_t)b * (N_ * 3);
    __shared__ float4 pts[N_];                         // 64 KB coord table
    __shared__ __align__(16) unsigned long long part[2][8];
    float px[8], py[8], pz[8], dd[8];
#pragma unroll
    for (int j = 0; j < 8; ++j) {
        int p = t + 512 * j;
        float x = X[p * 3 + 0], y = X[p * 3 + 1], z = X[p * 3 + 2];
        px[j] = x; py[j] = y; pz[j] = z; dd[j] = 1e10f;
        pts[p] = make_float4(x, y, z, 0.0f);
    }
    if (t == 0) {  // t==0,j==0 holds point 0 = first centroid
        new_xyz[(size_t)b * (S_ * 3) + 0] = px[0];
        new_xyz[(size_t)b * (S_ * 3) + 1] = py[0];
        new_xyz[(size_t)b * (S_ * 3) + 2] = pz[0];
    }
    __syncthreads();
    float4 cent = pts[0];
    for (int i = 1; i < S_; ++i) {
        float bd = -1.0f;
        int bp = 0;
#pragma unroll
        for (int j = 0; j < 8; ++j) {
            float d = sqdist_rn(px[j], py[j], pz[j], cent.x, cent.y, cent.z);
            dd[j] = fminf(dd[j], d);
            if (dd[j] > bd) { bd = dd[j]; bp = t + 512 * j; }  // ascending p -> first-max
        }
        // key: max dist wins; tie -> lower point index wins (matches np.argmax)
        unsigned long long key =
            ((unsigned long long)__float_as_uint(bd) << 32) |
            (unsigned long long)(~(unsigned)bp);
#pragma unroll
        for (int m = 32; m >= 1; m >>= 1) {
            unsigned long long o = __shfl_xor(key, m);
            if (o > key) key = o;
        }
        if ((t & 63) == 0) part[i & 1][t >> 6] = key;
        __syncthreads();
        // redundant final reduce in every thread -> no second barrier needed
        ulonglong2 q0 = *(const ulonglong2*)&part[i & 1][0];
        ulonglong2 q1 = *(const ulonglong2*)&part[i & 1][2];
        ulonglong2 q2 = *(const ulonglong2*)&part[i & 1][4];
        ulonglong2 q3 = *(const ulonglong2*)&part[i & 1][6];
        unsigned long long k = q0.x;
        if (q0.y > k) k = q0.y;
        if (q1.x > k) k = q1.x;
        if (q1.y > k) k = q1.y;
        if (q2.x > k) k = q2.x;
        if (q2.y > k) k = q2.y;
        if (q3.x > k) k = q3.x;
        if (q3.y > k) k = q3.y;
        unsigned gidx = ~(unsigned)(k & 0xFFFFFFFFull);
        cent = pts[gidx];  // uniform address -> LDS broadcast
        if (t == 0) {
            size_t o3 = ((size_t)b * S_ + i) * 3;
            new_xyz[o3 + 0] = cent.x;
            new_xyz[o3 + 1] = cent.y;
            new_xyz[o3 + 2] = cent.z;
        }
    }
}

// ---------------- Ball query: one wave per center, ordered compaction ----------------
__global__ __launch_bounds__(256) void qb_kernel(const float* __restrict__ xyz,
                                                 const float* __restrict__ new_xyz,
                                                 int* __restrict__ idxbuf) {
    const int c = blockIdx.x * 4 + (threadIdx.x >> 6);
    const int lane = threadIdx.x & 63;
    const int b = c >> 10;
    const float* X = xyz + (size_t)b * (N_ * 3);
    const float cx = new_xyz[c * 3 + 0];
    const float cy = new_xyz[c * 3 + 1];
    const float cz = new_xyz[c * 3 + 2];
    int* out = idxbuf + (size_t)c * K_;
    int taken = 0, first = -1;
    for (int ch = 0; ch < 64; ++ch) {
        int p = ch * 64 + lane;
        float d = sqdist_rn(X[p * 3 + 0], X[p * 3 + 1], X[p * 3 + 2], cx, cy, cz);
        bool ok = (d <= 0.25f);  // sqr > r^2 excluded => include <=
        unsigned long long m = __ballot(ok);
        if (first < 0 && m) first = ch * 64 + (__ffsll((unsigned long long)m) - 1);
        int pos = taken + (int)__popcll(m & ((1ull << lane) - 1ull));
        if (ok && pos < K_) out[pos] = p;
        taken += (int)__popcll(m);
        if (taken >= K_) break;
    }
    int filled = taken < K_ ? taken : K_;
    if (lane >= filled && lane < K_) out[lane] = first;
}

// ---------------- shared GEMM tile: 128 rows x (16*CC) outs, f32 register tile ----------------
template <int FS, int SLOTS, int CC>
DI void gemm_tile(const float* __restrict__ feat, const float* __restrict__ wl,
                  const float* __restrict__ bias, unsigned short* __restrict__ yout,
                  float* __restrict__ ps, float* __restrict__ pq,
                  int r0, int tid, int blk) {
    const int tr = tid & 15;
    const int tc = tid >> 4;
    float acc[8][CC];
#pragma unroll
    for (int rr = 0; rr < 8; ++rr)
#pragma unroll
        for (int cc = 0; cc < CC; ++cc) acc[rr][cc] = 0.0f;

#pragma unroll 2
    for (int sl = 0; sl < SLOTS; ++sl) {
        float4 xv[8], wv[CC];
#pragma unroll
        for (int rr = 0; rr < 8; ++rr)
            xv[rr] = *(const float4*)&feat[(tr + 16 * rr) * FS + 4 * sl];
#pragma unroll
        for (int cc = 0; cc < CC; ++cc)
            wv[cc] = *(const float4*)&wl[(tc + 16 * cc) * FS + 4 * sl];
#pragma unroll
        for (int rr = 0; rr < 8; ++rr)
#pragma unroll
            for (int cc = 0; cc < CC; ++cc)
                acc[rr][cc] = fmaf(xv[rr].x, wv[cc].x,
                               fmaf(xv[rr].y, wv[cc].y,
                                fmaf(xv[rr].z, wv[cc].z,
                                 fmaf(xv[rr].w, wv[cc].w, acc[rr][cc]))));
    }
    float s1[CC], s2[CC];
#pragma unroll
    for (int cc = 0; cc < CC; ++cc) {
        const int och = tc + 16 * cc;
        const float bv = bias[och];
        s1[cc] = 0.0f; s2[cc] = 0.0f;
#pragma unroll
        for (int rr = 0; rr < 8; ++rr) {
            float y = acc[rr][cc] + bv;
            const int gr = r0 + tr + 16 * rr;
            yout[(size_t)gr * (16 * CC) + och] = f2b(y);
            s1[cc] += y;
            s2[cc] = fmaf(y, y, s2[cc]);
        }
    }
    // lanes sharing tc butterfly over tr -> complete per-channel block totals, no atomics
#pragma unroll
    for (int m = 1; m < 16; m <<= 1) {
#pragma unroll
        for (int cc = 0; cc < CC; ++cc) {
            s1[cc] += __shfl_xor(s1[cc], m);
            s2[cc] += __shfl_xor(s2[cc], m);
        }
    }
    if ((tid & 15) == 0) {
#pragma unroll
        for (int cc = 0; cc < CC; ++cc) {
            const int och = tc + 16 * cc;
            ps[och * NBLK + blk] = s1[cc];
            pq[och * NBLK + blk] = s2[cc];
        }
    }
}

// ---------------- Layer 1: gather(xyz, xyz-center, points) + GEMM 70->64 ----------------
__global__ __launch_bounds__(256) void layer1_kernel(
    const float* __restrict__ xyz, const float* __restrict__ points,
    const float* __restrict__ new_xyz, const int* __restrict__ idxbuf,
    const float* __restrict__ W, const float* __restrict__ bias,
    unsigned short* __restrict__ yout, float* __restrict__ ps, float* __restrict__ pq) {
    const int tid = threadIdx.x;
    const int blk = blockIdx.x;
    const int r0 = blk * 128;
    __shared__ float feat[128 * 76];   // channels: 0..5 xyz/norm, 6..7 zero pad, 8..71 points
    __shared__ float wl[64 * 76];
    for (int jj = tid; jj < 64 * 70; jj += 256) {
        int o = jj / 70;
        int i = jj - o * 70;
        int mch = (i < 6) ? i : (i + 2);
        wl[o * 76 + mch] = W[jj];
    }
    if (tid < 128) wl[(tid >> 1) * 76 + 6 + (tid & 1)] = 0.0f;
    {
        const int row = tid >> 1, h = tid & 1;
        const int gr = r0 + row;
        const int b = gr >> 15;
        const int s = (gr >> 5) & 1023;
        const int pi = idxbuf[gr];
        const float* P = points + ((size_t)b * N_ + pi) * 64 + h * 32;
        float* fr = &feat[row * 76];
#pragma unroll
        for (int q = 0; q < 8; ++q) {
            float4 v = *(const float4*)(P + 4 * q);
            *(float4*)(fr + 8 + h * 32 + 4 * q) = v;
        }
        if (h == 0) {
            size_t pb = ((size_t)b * N_ + pi) * 3;
            float x = xyz[pb + 0], y = xyz[pb + 1], z = xyz[pb + 2];
            const float* C = new_xyz + ((size_t)b * S_ + s) * 3;
            fr[0] = x; fr[1] = y; fr[2] = z;
            fr[3] = x - C[0]; fr[4] = y - C[1]; fr[5] = z - C[2];
            fr[6] = 0.0f; fr[7] = 0.0f;
        }
    }
    __syncthreads();
    gemm_tile<76, 18, 4>(feat, wl, bias, yout, ps, pq, r0, tid, blk);
}

// ---------------- Layers 2/3: BN(prev)+ReLU on load, GEMM 64->OC ----------------
template <int OC>
__global__ __launch_bounds__(256) void layer23_kernel(
    const unsigned short* __restrict__ yin,
    const float* __restrict__ scale, const float* __restrict__ shift,
    const float* __restrict__ W, const float* __restrict__ bias,
    unsigned short* __restrict__ yout, float* __restrict__ ps, float* __restrict__ pq) {
    const int tid = threadIdx.x;
    const int blk = blockIdx.x;
    const int r0 = blk * 128;
    __shared__ float feat[128 * 68];
    __shared__ float wl[OC * 68];
    __shared__ float ssc[64], ssh[64];
    if (tid < 64) { ssc[tid] = scale[tid]; ssh[tid] = shift[tid]; }
    for (int jj = tid; jj < OC * 64; jj += 256) {
        int o = jj >> 6, i = jj & 63;
        wl[o * 68 + i] = W[jj];
    }
    __syncthreads();
    {
        const int row = tid >> 1, h = tid & 1;
        const int gr = r0 + row;
        const uint4* src = (const uint4*)(yin + (size_t)gr * 64 + h * 32);
        float* fr = &feat[row * 68 + h * 32];
#pragma unroll
        for (int q = 0; q < 4; ++q) {
            uint4 u = src[q];
            const int cb = h * 32 + q * 8;
            float f0 = fmaxf(fmaf(__uint_as_float(u.x << 16),         ssc[cb + 0], ssh[cb + 0]), 0.f);
            float f1 = fmaxf(fmaf(__uint_as_float(u.x & 0xFFFF0000u), ssc[cb + 1], ssh[cb + 1]), 0.f);
            float f2 = fmaxf(fmaf(__uint_as_float(u.y << 16),         ssc[cb + 2], ssh[cb + 2]), 0.f);
            float f3 = fmaxf(fmaf(__uint_as_float(u.y & 0xFFFF0000u), ssc[cb + 3], ssh[cb + 3]), 0.f);
            float f4 = fmaxf(fmaf(__uint_as_float(u.z << 16),         ssc[cb + 4], ssh[cb + 4]), 0.f);
            float f5 = fmaxf(fmaf(__uint_as_float(u.z & 0xFFFF0000u), ssc[cb + 5], ssh[cb + 5]), 0.f);
            float f6 = fmaxf(fmaf(__uint_as_float(u.w << 16),         ssc[cb + 6], ssh[cb + 6]), 0.f);
            float f7 = fmaxf(fmaf(__uint_as_float(u.w & 0xFFFF0000u), ssc[cb + 7], ssh[cb + 7]), 0.f);
            *(float4*)(fr + 8 * q)     = make_float4(f0, f1, f2, f3);
            *(float4*)(fr + 8 * q + 4) = make_float4(f4, f5, f6, f7);
        }
    }
    __syncthreads();
    gemm_tile<68, 16, OC / 16>(feat, wl, bias, yout, ps, pq, r0, tid, blk);
}

// ---------------- BN stats reduce -> scale/shift ----------------
__global__ __launch_bounds__(256) void bn_reduce_kernel(
    const float* __restrict__ ps, const float* __restrict__ pq,
    const float* __restrict__ gamma, const float* __restrict__ beta,
    float* __restrict__ scale, float* __restrict__ shift) {
    const int o = blockIdx.x, t = threadIdx.x;
    float s1 = 0.f, s2 = 0.f;
    for (int i = t; i < NBLK; i += 256) {
        s1 += ps[o * NBLK + i];
        s2 += pq[o * NBLK + i];
    }
#pragma unroll
    for (int m = 32; m >= 1; m >>= 1) { s1 += __shfl_xor(s1, m); s2 += __shfl_xor(s2, m); }
    __shared__ float a1[4], a2[4];
    if ((t & 63) == 0) { a1[t >> 6] = s1; a2[t >> 6] = s2; }
    __syncthreads();
    if (t == 0) {
        float S1 = a1[0] + a1[1] + a1[2] + a1[3];
        float S2 = a2[0] + a2[1] + a2[2] + a2[3];
        const float inv = 1.0f / (float)M_TOT;
        float mean = S1 * inv;
        float var = S2 * inv - mean * mean;
        if (var < 0.f) var = 0.f;
        float rstd = 1.0f / sqrtf(var + 1e-5f);
        float sc = rstd * gamma[o];
        scale[o] = sc;
        shift[o] = beta[o] - mean * sc;
    }
}

// ---------------- BN3 + ReLU + max over K ----------------
__global__ __launch_bounds__(256) void pool_kernel(
    const unsigned short* __restrict__ y3,
    const float* __restrict__ scale, const float* __restrict__ shift,
    float* __restrict__ outp) {
    const int grp = blockIdx.x * 2 + (threadIdx.x >> 7);
    const int ch = threadIdx.x & 127;
    const unsigned short* Y = y3 + (size_t)grp * (K_ * 128) + ch;
    const float sc = scale[ch], sh = shift[ch];
    float m = -1e30f;
#pragma unroll 8
    for (int k = 0; k < K_; ++k) {
        float v = b2f(Y[k * 128]);
        m = fmaxf(m, fmaf(v, sc, sh));
    }
    outp[(size_t)grp * 128 + ch] = fmaxf(m, 0.0f);  // relu commutes with max
}

extern "C" void kernel_launch(void* const* d_in, const int* in_sizes, int n_in,
                              void* d_out, int out_size, void* d_ws, size_t ws_size,
                              hipStream_t stream) {
    const float* xyz    = (const float*)d_in[0];
    const float* points = (const float*)d_in[1];
    const float* w0  = (const float*)d_in[2];
    const float* b0  = (const float*)d_in[3];
    const float* g0  = (const float*)d_in[4];
    const float* be0 = (const float*)d_in[5];
    const float* w1  = (const float*)d_in[6];
    const float* b1  = (const float*)d_in[7];
    const float* g1  = (const float*)d_in[8];
    const float* be1 = (const float*)d_in[9];
    const float* w2  = (const float*)d_in[10];
    const float* b2  = (const float*)d_in[11];
    const float* g2  = (const float*)d_in[12];
    const float* be2 = (const float*)d_in[13];

    float* out = (float*)d_out;           // [0,24576) new_xyz, [24576,...) new_points
    char* ws = (char*)d_ws;
    int*   idxbuf = (int*)ws;                              // 1 MB
    float* ps  = (float*)(ws + (1 << 20));                 // 1 MB (128ch x 2048 blk)
    float* pq  = (float*)(ws + (2 << 20));                 // 1 MB
    float* st  = (float*)(ws + (3 << 20));                 // scale/shift x3 layers
    float *sc0 = st,        *sh0 = st + 128;
    float *sc1 = st + 256,  *sh1 = st + 384;
    float *sc2 = st + 512,  *sh2 = st + 640;
    unsigned short* y1 = (unsigned short*)(ws + (4 << 20));   // 32 MB (bf16)
    unsigned short* y3 = y1;                                  // 64 MB, reuses y1 (dead)
    unsigned short* y2 = (unsigned short*)(ws + (68 << 20));  // 32 MB
    // total ws footprint: 100 MB

    fps_kernel<<<8, 512, 0, stream>>>(xyz, out);
    qb_kernel<<<2048, 256, 0, stream>>>(xyz, out, idxbuf);
    layer1_kernel<<<NBLK, 256, 0, stream>>>(xyz, points, out, idxbuf, w0, b0, y1, ps, pq);
    bn_reduce_kernel<<<64, 256, 0, stream>>>(ps, pq, g0, be0, sc0, sh0);
    layer23_kernel<64><<<NBLK, 256, 0, stream>>>(y1, sc0, sh0, w1, b1, y2, ps, pq);
    bn_reduce_kernel<<<64, 256, 0, stream>>>(ps, pq, g1, be1, sc1, sh1);
    layer23_kernel<128><<<NBLK, 256, 0, stream>>>(y2, sc1, sh1, w2, b2, y3, ps, pq);
    bn_reduce_kernel<<<128, 256, 0, stream>>>(ps, pq, g2, be2, sc2, sh2);
    pool_kernel<<<4096, 256, 0, stream>>>(y3, sc2, sh2, out + 24576);
}

// Round 3
// 968.857 us; speedup vs baseline: 1.4709x; 1.1775x over previous
//
#include <hip/hip_runtime.h>

#define DI __device__ __forceinline__

#define B_ 8
#define N_ 4096
#define S_ 1024
#define K_ 32
#define M_TOT (B_ * S_ * K_)   // 262144 rows
#define NBLK 2048              // M_TOT / 128

// Exact-IEEE squared distance, matching numpy f32 eval order ((dx*dx+dy*dy)+dz*dz),
// _rn intrinsics block FMA contraction so indices match the reference bit-exactly.
DI float sqdist_rn(float ax, float ay, float az, float bx, float by, float bz) {
    float dx = __fsub_rn(ax, bx);
    float dy = __fsub_rn(ay, by);
    float dz = __fsub_rn(az, bz);
    return __fadd_rn(__fadd_rn(__fmul_rn(dx, dx), __fmul_rn(dy, dy)), __fmul_rn(dz, dz));
}

DI unsigned short f2b(float f) {  // f32 -> bf16 RNE
    unsigned u = __float_as_uint(f);
    return (unsigned short)((u + 0x7FFFu + ((u >> 16) & 1u)) >> 16);
}
DI float b2f(unsigned short h) { return __uint_as_float(((unsigned)h) << 16); }

// DPP permutation applied to a u64 as two 32-bit halves (VALU-speed cross-lane).
template <int CTRL>
DI unsigned long long dpp_u64(unsigned long long v) {
    unsigned lo = (unsigned)__builtin_amdgcn_update_dpp(
        0, (int)(unsigned)v, CTRL, 0xF, 0xF, true);
    unsigned hi = (unsigned)__builtin_amdgcn_update_dpp(
        0, (int)(unsigned)(v >> 32), CTRL, 0xF, 0xF, true);
    return ((unsigned long long)hi << 32) | lo;
}
DI unsigned long long umax64(unsigned long long a, unsigned long long b) {
    return a > b ? a : b;
}

// ---------------- FPS: one block per batch, 1 barrier/step, DPP wave reduce ----------------
// Per step: per-lane key tree (u64 packed dist|~idx) -> 6-stage DPP reduce to lane 63
// (row_shr 1/2/4/8 + row_bcast15/31; max is idempotent so prefix combines are safe)
// -> lane63 writes wave partial -> barrier -> all threads redundantly reduce 8 partials
// -> broadcast LDS read of winner coords. Partials double-buffered (one barrier/step).
__global__ __launch_bounds__(512) void fps_kernel(const float* __restrict__ xyz,
                                                  float* __restrict__ new_xyz) {
    const int b = blockIdx.x;
    const int t = threadIdx.x;
    const float* X = xyz + (size_t)b * (N_ * 3);
    __shared__ float4 pts[N_];                         // 64 KB coord table
    __shared__ __align__(16) unsigned long long part[2][8];
    float px[8], py[8], pz[8], dd[8];
#pragma unroll
    for (int j = 0; j < 8; ++j) {
        int p = t + 512 * j;
        float x = X[p * 3 + 0], y = X[p * 3 + 1], z = X[p * 3 + 2];
        px[j] = x; py[j] = y; pz[j] = z; dd[j] = 1e10f;
        pts[p] = make_float4(x, y, z, 0.0f);
    }
    if (t == 0) {  // t==0,j==0 holds point 0 = first centroid
        new_xyz[(size_t)b * (S_ * 3) + 0] = px[0];
        new_xyz[(size_t)b * (S_ * 3) + 1] = py[0];
        new_xyz[(size_t)b * (S_ * 3) + 2] = pz[0];
    }
    __syncthreads();
    float4 cent = pts[0];
    for (int i = 1; i < S_; ++i) {
        // per-lane packed keys; u64 max = max dist, tie -> lower point index (np.argmax)
        unsigned long long k0[8];
#pragma unroll
        for (int j = 0; j < 8; ++j) {
            float d = sqdist_rn(px[j], py[j], pz[j], cent.x, cent.y, cent.z);
            dd[j] = fminf(dd[j], d);
            k0[j] = ((unsigned long long)__float_as_uint(dd[j]) << 32) |
                    (unsigned long long)(~(unsigned)(t + 512 * j));
        }
        k0[0] = umax64(k0[0], k0[1]);
        k0[2] = umax64(k0[2], k0[3]);
        k0[4] = umax64(k0[4], k0[5]);
        k0[6] = umax64(k0[6], k0[7]);
        k0[0] = umax64(k0[0], k0[2]);
        k0[4] = umax64(k0[4], k0[6]);
        unsigned long long key = umax64(k0[0], k0[4]);
        // wave reduce to lane 63, VALU DPP (no LDS pipe)
        key = umax64(key, dpp_u64<0x111>(key));  // row_shr:1
        key = umax64(key, dpp_u64<0x112>(key));  // row_shr:2
        key = umax64(key, dpp_u64<0x114>(key));  // row_shr:4
        key = umax64(key, dpp_u64<0x118>(key));  // row_shr:8
        key = umax64(key, dpp_u64<0x142>(key));  // row_bcast15
        key = umax64(key, dpp_u64<0x143>(key));  // row_bcast31
        if ((t & 63) == 63) part[i & 1][t >> 6] = key;
        __syncthreads();
        // redundant final reduce in every thread -> no second barrier needed
        ulonglong2 q0 = *(const ulonglong2*)&part[i & 1][0];
        ulonglong2 q1 = *(const ulonglong2*)&part[i & 1][2];
        ulonglong2 q2 = *(const ulonglong2*)&part[i & 1][4];
        ulonglong2 q3 = *(const ulonglong2*)&part[i & 1][6];
        unsigned long long ka = umax64(umax64(q0.x, q0.y), umax64(q1.x, q1.y));
        unsigned long long kb = umax64(umax64(q2.x, q2.y), umax64(q3.x, q3.y));
        unsigned long long k = umax64(ka, kb);
        unsigned gidx = ~(unsigned)(k & 0xFFFFFFFFull);
        cent = pts[gidx];  // uniform address -> LDS broadcast
        if (t == 0) {
            size_t o3 = ((size_t)b * S_ + i) * 3;
            new_xyz[o3 + 0] = cent.x;
            new_xyz[o3 + 1] = cent.y;
            new_xyz[o3 + 2] = cent.z;
        }
    }
}

// ---------------- Ball query: one wave per center, ordered compaction ----------------
__global__ __launch_bounds__(256) void qb_kernel(const float* __restrict__ xyz,
                                                 const float* __restrict__ new_xyz,
                                                 int* __restrict__ idxbuf) {
    const int c = blockIdx.x * 4 + (threadIdx.x >> 6);
    const int lane = threadIdx.x & 63;
    const int b = c >> 10;
    const float* X = xyz + (size_t)b * (N_ * 3);
    const float cx = new_xyz[c * 3 + 0];
    const float cy = new_xyz[c * 3 + 1];
    const float cz = new_xyz[c * 3 + 2];
    int* out = idxbuf + (size_t)c * K_;
    int taken = 0, first = -1;
    for (int ch = 0; ch < 64; ++ch) {
        int p = ch * 64 + lane;
        float d = sqdist_rn(X[p * 3 + 0], X[p * 3 + 1], X[p * 3 + 2], cx, cy, cz);
        bool ok = (d <= 0.25f);  // sqr > r^2 excluded => include <=
        unsigned long long m = __ballot(ok);
        if (first < 0 && m) first = ch * 64 + (__ffsll((unsigned long long)m) - 1);
        int pos = taken + (int)__popcll(m & ((1ull << lane) - 1ull));
        if (ok && pos < K_) out[pos] = p;
        taken += (int)__popcll(m);
        if (taken >= K_) break;
    }
    int filled = taken < K_ ? taken : K_;
    if (lane >= filled && lane < K_) out[lane] = first;
}

// ---------------- shared GEMM tile: 128 rows x (16*CC) outs, f32 register tile ----------------
template <int FS, int SLOTS, int CC>
DI void gemm_tile(const float* __restrict__ feat, const float* __restrict__ wl,
                  const float* __restrict__ bias, unsigned short* __restrict__ yout,
                  float* __restrict__ ps, float* __restrict__ pq,
                  int r0, int tid, int blk) {
    const int tr = tid & 15;
    const int tc = tid >> 4;
    float acc[8][CC];
#pragma unroll
    for (int rr = 0; rr < 8; ++rr)
#pragma unroll
        for (int cc = 0; cc < CC; ++cc) acc[rr][cc] = 0.0f;

#pragma unroll 2
    for (int sl = 0; sl < SLOTS; ++sl) {
        float4 xv[8], wv[CC];
#pragma unroll
        for (int rr = 0; rr < 8; ++rr)
            xv[rr] = *(const float4*)&feat[(tr + 16 * rr) * FS + 4 * sl];
#pragma unroll
        for (int cc = 0; cc < CC; ++cc)
            wv[cc] = *(const float4*)&wl[(tc + 16 * cc) * FS + 4 * sl];
#pragma unroll
        for (int rr = 0; rr < 8; ++rr)
#pragma unroll
            for (int cc = 0; cc < CC; ++cc)
                acc[rr][cc] = fmaf(xv[rr].x, wv[cc].x,
                               fmaf(xv[rr].y, wv[cc].y,
                                fmaf(xv[rr].z, wv[cc].z,
                                 fmaf(xv[rr].w, wv[cc].w, acc[rr][cc]))));
    }
    float s1[CC], s2[CC];
#pragma unroll
    for (int cc = 0; cc < CC; ++cc) {
        const int och = tc + 16 * cc;
        const float bv = bias[och];
        s1[cc] = 0.0f; s2[cc] = 0.0f;
#pragma unroll
        for (int rr = 0; rr < 8; ++rr) {
            float y = acc[rr][cc] + bv;
            const int gr = r0 + tr + 16 * rr;
            yout[(size_t)gr * (16 * CC) + och] = f2b(y);
            s1[cc] += y;
            s2[cc] = fmaf(y, y, s2[cc]);
        }
    }
    // lanes sharing tc butterfly over tr -> complete per-channel block totals, no atomics
#pragma unroll
    for (int m = 1; m < 16; m <<= 1) {
#pragma unroll
        for (int cc = 0; cc < CC; ++cc) {
            s1[cc] += __shfl_xor(s1[cc], m);
            s2[cc] += __shfl_xor(s2[cc], m);
        }
    }
    if ((tid & 15) == 0) {
#pragma unroll
        for (int cc = 0; cc < CC; ++cc) {
            const int och = tc + 16 * cc;
            ps[och * NBLK + blk] = s1[cc];
            pq[och * NBLK + blk] = s2[cc];
        }
    }
}

// ---------------- Layer 1: gather(xyz, xyz-center, points) + GEMM 70->64 ----------------
__global__ __launch_bounds__(256) void layer1_kernel(
    const float* __restrict__ xyz, const float* __restrict__ points,
    const float* __restrict__ new_xyz, const int* __restrict__ idxbuf,
    const float* __restrict__ W, const float* __restrict__ bias,
    unsigned short* __restrict__ yout, float* __restrict__ ps, float* __restrict__ pq) {
    const int tid = threadIdx.x;
    const int blk = blockIdx.x;
    const int r0 = blk * 128;
    __shared__ float feat[128 * 76];   // channels: 0..5 xyz/norm, 6..7 zero pad, 8..71 points
    __shared__ float wl[64 * 76];
    for (int jj = tid; jj < 64 * 70; jj += 256) {
        int o = jj / 70;
        int i = jj - o * 70;
        int mch = (i < 6) ? i : (i + 2);
        wl[o * 76 + mch] = W[jj];
    }
    if (tid < 128) wl[(tid >> 1) * 76 + 6 + (tid & 1)] = 0.0f;
    {
        const int row = tid >> 1, h = tid & 1;
        const int gr = r0 + row;
        const int b = gr >> 15;
        const int s = (gr >> 5) & 1023;
        const int pi = idxbuf[gr];
        const float* P = points + ((size_t)b * N_ + pi) * 64 + h * 32;
        float* fr = &feat[row * 76];
#pragma unroll
        for (int q = 0; q < 8; ++q) {
            float4 v = *(const float4*)(P + 4 * q);
            *(float4*)(fr + 8 + h * 32 + 4 * q) = v;
        }
        if (h == 0) {
            size_t pb = ((size_t)b * N_ + pi) * 3;
            float x = xyz[pb + 0], y = xyz[pb + 1], z = xyz[pb + 2];
            const float* C = new_xyz + ((size_t)b * S_ + s) * 3;
            fr[0] = x; fr[1] = y; fr[2] = z;
            fr[3] = x - C[0]; fr[4] = y - C[1]; fr[5] = z - C[2];
            fr[6] = 0.0f; fr[7] = 0.0f;
        }
    }
    __syncthreads();
    gemm_tile<76, 18, 4>(feat, wl, bias, yout, ps, pq, r0, tid, blk);
}

// ---------------- Layers 2/3: BN(prev)+ReLU on load, GEMM 64->OC ----------------
template <int OC>
__global__ __launch_bounds__(256) void layer23_kernel(
    const unsigned short* __restrict__ yin,
    const float* __restrict__ scale, const float* __restrict__ shift,
    const float* __restrict__ W, const float* __restrict__ bias,
    unsigned short* __restrict__ yout, float* __restrict__ ps, float* __restrict__ pq) {
    const int tid = threadIdx.x;
    const int blk = blockIdx.x;
    const int r0 = blk * 128;
    __shared__ float feat[128 * 68];
    __shared__ float wl[OC * 68];
    __shared__ float ssc[64], ssh[64];
    if (tid < 64) { ssc[tid] = scale[tid]; ssh[tid] = shift[tid]; }
    for (int jj = tid; jj < OC * 64; jj += 256) {
        int o = jj >> 6, i = jj & 63;
        wl[o * 68 + i] = W[jj];
    }
    __syncthreads();
    {
        const int row = tid >> 1, h = tid & 1;
        const int gr = r0 + row;
        const uint4* src = (const uint4*)(yin + (size_t)gr * 64 + h * 32);
        float* fr = &feat[row * 68 + h * 32];
#pragma unroll
        for (int q = 0; q < 4; ++q) {
            uint4 u = src[q];
            const int cb = h * 32 + q * 8;
            float f0 = fmaxf(fmaf(__uint_as_float(u.x << 16),         ssc[cb + 0], ssh[cb + 0]), 0.f);
            float f1 = fmaxf(fmaf(__uint_as_float(u.x & 0xFFFF0000u), ssc[cb + 1], ssh[cb + 1]), 0.f);
            float f2 = fmaxf(fmaf(__uint_as_float(u.y << 16),         ssc[cb + 2], ssh[cb + 2]), 0.f);
            float f3 = fmaxf(fmaf(__uint_as_float(u.y & 0xFFFF0000u), ssc[cb + 3], ssh[cb + 3]), 0.f);
            float f4 = fmaxf(fmaf(__uint_as_float(u.z << 16),         ssc[cb + 4], ssh[cb + 4]), 0.f);
            float f5 = fmaxf(fmaf(__uint_as_float(u.z & 0xFFFF0000u), ssc[cb + 5], ssh[cb + 5]), 0.f);
            float f6 = fmaxf(fmaf(__uint_as_float(u.w << 16),         ssc[cb + 6], ssh[cb + 6]), 0.f);
            float f7 = fmaxf(fmaf(__uint_as_float(u.w & 0xFFFF0000u), ssc[cb + 7], ssh[cb + 7]), 0.f);
            *(float4*)(fr + 8 * q)     = make_float4(f0, f1, f2, f3);
            *(float4*)(fr + 8 * q + 4) = make_float4(f4, f5, f6, f7);
        }
    }
    __syncthreads();
    gemm_tile<68, 16, OC / 16>(feat, wl, bias, yout, ps, pq, r0, tid, blk);
}

// ---------------- BN stats reduce -> scale/shift ----------------
__global__ __launch_bounds__(256) void bn_reduce_kernel(
    const float* __restrict__ ps, const float* __restrict__ pq,
    const float* __restrict__ gamma, const float* __restrict__ beta,
    float* __restrict__ scale, float* __restrict__ shift) {
    const int o = blockIdx.x, t = threadIdx.x;
    float s1 = 0.f, s2 = 0.f;
    for (int i = t; i < NBLK; i += 256) {
        s1 += ps[o * NBLK + i];
        s2 += pq[o * NBLK + i];
    }
#pragma unroll
    for (int m = 32; m >= 1; m >>= 1) { s1 += __shfl_xor(s1, m); s2 += __shfl_xor(s2, m); }
    __shared__ float a1[4], a2[4];
    if ((t & 63) == 0) { a1[t >> 6] = s1; a2[t >> 6] = s2; }
    __syncthreads();
    if (t == 0) {
        float S1 = a1[0] + a1[1] + a1[2] + a1[3];
        float S2 = a2[0] + a2[1] + a2[2] + a2[3];
        const float inv = 1.0f / (float)M_TOT;
        float mean = S1 * inv;
        float var = S2 * inv - mean * mean;
        if (var < 0.f) var = 0.f;
        float rstd = 1.0f / sqrtf(var + 1e-5f);
        float sc = rstd * gamma[o];
        scale[o] = sc;
        shift[o] = beta[o] - mean * sc;
    }
}

// ---------------- BN3 + ReLU + max over K ----------------
__global__ __launch_bounds__(256) void pool_kernel(
    const unsigned short* __restrict__ y3,
    const float* __restrict__ scale, const float* __restrict__ shift,
    float* __restrict__ outp) {
    const int grp = blockIdx.x * 2 + (threadIdx.x >> 7);
    const int ch = threadIdx.x & 127;
    const unsigned short* Y = y3 + (size_t)grp * (K_ * 128) + ch;
    const float sc = scale[ch], sh = shift[ch];
    float m = -1e30f;
#pragma unroll 8
    for (int k = 0; k < K_; ++k) {
        float v = b2f(Y[k * 128]);
        m = fmaxf(m, fmaf(v, sc, sh));
    }
    outp[(size_t)grp * 128 + ch] = fmaxf(m, 0.0f);  // relu commutes with max
}

extern "C" void kernel_launch(void* const* d_in, const int* in_sizes, int n_in,
                              void* d_out, int out_size, void* d_ws, size_t ws_size,
                              hipStream_t stream) {
    const float* xyz    = (const float*)d_in[0];
    const float* points = (const float*)d_in[1];
    const float* w0  = (const float*)d_in[2];
    const float* b0  = (const float*)d_in[3];
    const float* g0  = (const float*)d_in[4];
    const float* be0 = (const float*)d_in[5];
    const float* w1  = (const float*)d_in[6];
    const float* b1  = (const float*)d_in[7];
    const float* g1  = (const float*)d_in[8];
    const float* be1 = (const float*)d_in[9];
    const float* w2  = (const float*)d_in[10];
    const float* b2  = (const float*)d_in[11];
    const float* g2  = (const float*)d_in[12];
    const float* be2 = (const float*)d_in[13];

    float* out = (float*)d_out;           // [0,24576) new_xyz, [24576,...) new_points
    char* ws = (char*)d_ws;
    int*   idxbuf = (int*)ws;                              // 1 MB
    float* ps  = (float*)(ws + (1 << 20));                 // 1 MB (128ch x 2048 blk)
    float* pq  = (float*)(ws + (2 << 20));                 // 1 MB
    float* st  = (float*)(ws + (3 << 20));                 // scale/shift x3 layers
    float *sc0 = st,        *sh0 = st + 128;
    float *sc1 = st + 256,  *sh1 = st + 384;
    float *sc2 = st + 512,  *sh2 = st + 640;
    unsigned short* y1 = (unsigned short*)(ws + (4 << 20));   // 32 MB (bf16)
    unsigned short* y3 = y1;                                  // 64 MB, reuses y1 (dead)
    unsigned short* y2 = (unsigned short*)(ws + (68 << 20));  // 32 MB
    // total ws footprint: 100 MB

    fps_kernel<<<8, 512, 0, stream>>>(xyz, out);
    qb_kernel<<<2048, 256, 0, stream>>>(xyz, out, idxbuf);
    layer1_kernel<<<NBLK, 256, 0, stream>>>(xyz, points, out, idxbuf, w0, b0, y1, ps, pq);
    bn_reduce_kernel<<<64, 256, 0, stream>>>(ps, pq, g0, be0, sc0, sh0);
    layer23_kernel<64><<<NBLK, 256, 0, stream>>>(y1, sc0, sh0, w1, b1, y2, ps, pq);
    bn_reduce_kernel<<<64, 256, 0, stream>>>(ps, pq, g1, be1, sc1, sh1);
    layer23_kernel<128><<<NBLK, 256, 0, stream>>>(y2, sc1, sh1, w2, b2, y3, ps, pq);
    bn_reduce_kernel<<<128, 256, 0, stream>>>(ps, pq, g2, be2, sc2, sh2);
    pool_kernel<<<4096, 256, 0, stream>>>(y3, sc2, sh2, out + 24576);
}